// Round 2
// baseline (19053.651 us; speedup 1.0000x reference)
//
#include <hip/hip_runtime.h>

typedef unsigned short ushort_t;
typedef unsigned int uint32;
typedef __attribute__((ext_vector_type(8))) short bf16x8;
typedef __attribute__((ext_vector_type(8))) unsigned short ushort8;
typedef __attribute__((ext_vector_type(4))) float f32x4;

#define Bsz 128
#define T_STEPS 512
#define D_IN 128
#define H_DIM 384
#define G_DIM 1542
#define CONV_W 10
#define HB_ROW 49152   // Bsz*H_DIM
#define TP 521         // T+9 (9 zero-pad rows in front)

__device__ __forceinline__ float bf2f(ushort_t u) {
  return __builtin_bit_cast(float, (uint32)u << 16);
}
__device__ __forceinline__ ushort_t f2bf(float f) {
  uint32 u = __builtin_bit_cast(uint32, f);
  u += 0x7fffu + ((u >> 16) & 1u);
  return (ushort_t)(u >> 16);
}
__device__ __forceinline__ float sigf(float x) { return 1.f / (1.f + __expf(-x)); }
__device__ __forceinline__ float tanh_f(float x) { return 1.f - 2.f / (1.f + __expf(2.f * x)); }
// dtype-generic load: flag!=0 -> float32 source, else bf16 source
__device__ __forceinline__ float ldg_f(const void* p, size_t i, int f32) {
  return f32 ? ((const float*)p)[i] : bf2f(((const ushort_t*)p)[i]);
}

// ---------------- dtype detector: low-half-of-word sanity test ----------------
__global__ __launch_bounds__(64) void k_detect(const uint32* __restrict__ xw, int* __restrict__ dflag) {
  int lane = threadIdx.x;
  int cnt = 0;
  for (int i = 0; i < 16; ++i) {
    uint32 v = xw[lane * 16 + i];
    uint32 e = (v >> 7) & 0xFFu;   // biased exponent of LOW bf16 half
    cnt += (e == 0u || (e >= 0x70u && e <= 0x8Eu)) ? 1 : 0;
  }
  for (int off = 32; off; off >>= 1) cnt += __shfl_down(cnt, off);
  if (lane == 0) dflag[0] = (cnt < 700) ? 1 : 0;   // 1=f32, 0=bf16 (1024 samples)
}

// ---------------- init: zero pads / state / flags ----------------
__global__ __launch_bounds__(256) void k_zero(ushort_t* Hb, float* CD, float* cst, int* flags) {
  int idx = blockIdx.x * 256 + threadIdx.x;
  if (idx < 9 * HB_ROW) Hb[idx] = 0;          // h pad rows t=-9..-1
  if (idx < 9 * Bsz) CD[idx] = 0.f;           // cur_dist pad
  if (idx < Bsz * H_DIM) cst[idx] = 0.f;      // c state
  if (idx < 256) flags[idx] = 0;              // barrier flags (192 used)
}

// ---------------- pack recurrent weights: Wt[c][k], bias_acc[c] ----------------
__global__ __launch_bounds__(256) void k_packwt(const void* __restrict__ Wk, const void* __restrict__ bk,
                                                const void* __restrict__ Wr, const void* __restrict__ br,
                                                ushort_t* __restrict__ Wt, float* __restrict__ bias,
                                                const int* __restrict__ dflag) {
  const int is32 = dflag[0];
  int idx = blockIdx.x * 256 + threadIdx.x;   // 1552*512
  int c = idx >> 9, k = idx & 511;
  int xc = (c < 1536) ? (c + 6) : (c - 1536);
  float v = 0.f;
  if (c < 1542)
    v = (k < 384) ? ldg_f(Wr, (size_t)k * G_DIM + xc, is32)
                  : ldg_f(Wk, (size_t)(k - 384) * G_DIM + xc, is32);
  Wt[idx] = f2bf(v);
  if (k == 0) {
    float bv = 0.f;
    if (c < 1542)
      bv = ldg_f(bk, xc, is32) + ldg_f(br, xc, is32)
         + ldg_f(Wk, (size_t)128 * G_DIM + xc, is32) + ldg_f(Wr, (size_t)384 * G_DIM + xc, is32);
    bias[c] = bv;
  }
}

// ---------------- pack conv weights: Wp[o][k*384+i] = Wc[o][i][k] ----------------
__global__ __launch_bounds__(256) void k_packwp(const void* __restrict__ Wc, ushort_t* __restrict__ Wp,
                                                const int* __restrict__ dflag) {
  const int is32 = dflag[0];
  int idx = blockIdx.x * 256 + threadIdx.x;   // 384*3840
  int o = idx / 3840, kk = idx % 3840;
  int k = kk / 384, i = kk % 384;
  Wp[idx] = f2bf(ldg_f(Wc, (size_t)o * 3840 + i * CONV_W + k, is32));
}

// ---------------- pack small tensors into canonical forms ----------------
__global__ __launch_bounds__(256) void k_packsml(const void* Ws, const void* bs, const void* Wrs,
                                                 const void* brs, const void* bc,
                                                 ushort_t* Wsb, float* bsf, ushort_t* Wrsb,
                                                 float* brsf, float* bcf, const int* dflag) {
  const int is32 = dflag[0];
  int idx = blockIdx.x * 256 + threadIdx.x;
  if (idx < 24576) Wsb[idx] = f2bf(ldg_f(Ws, idx, is32));
  else if (idx < 49152) Wrsb[idx - 24576] = f2bf(ldg_f(Wrs, idx - 24576, is32));
  else if (idx < 49152 + 64) bsf[idx - 49152] = ldg_f(bs, idx - 49152, is32);
  else if (idx < 49216 + 384) brsf[idx - 49216] = ldg_f(brs, idx - 49216, is32);
  else if (idx < 49600 + 384) bcf[idx - 49600] = ldg_f(bc, idx - 49600, is32);
}

// ---------------- phase A: persistent sequential recurrence ----------------
// 192 blocks = 8 m-tiles (16 b-rows) x 3 levels x 8 j-groups (16 chunk cols).
__global__ __launch_bounds__(256) void k_phaseA(const void* __restrict__ xv,
                                                const ushort_t* __restrict__ Wt,
                                                const float* __restrict__ bias,
                                                ushort_t* __restrict__ Hb,
                                                float* __restrict__ CD,
                                                float* __restrict__ cst,
                                                int* __restrict__ flags,
                                                const int* __restrict__ dflag) {
  __shared__ float zbuf[5][16][17];   // 4 gate tiles + masters, padded
  const int is32 = dflag[0];
  const int bid = blockIdx.x;
  const int mt = bid / 24;
  const int unit = bid % 24;
  const int lv = unit / 8, jg = unit % 8;
  const int tid = threadIdx.x;
  const int w = tid >> 6, lane = tid & 63;
  const int l15 = lane & 15, quad = lane >> 4;

  const int brow = mt * 16 + l15;
  const int cb = (lv + 3 * w) * 128 + jg * 16;          // wave w: gate g=w (f,i,o,cin)
  const ushort_t* bptr = Wt + (size_t)(cb + l15) * 512 + quad * 8;
  const ushort_t* mwptr = Wt + (size_t)(1536 + l15) * 512 + quad * 8;
  const size_t xoff = (size_t)brow * (T_STEPS * D_IN) + quad * 8;
  const ushort_t* xu = (const ushort_t*)xv;
  const float* xf = (const float*)xv;
  const float biasg = bias[cb + l15];
  const float biasm = bias[1536 + l15];

  const int b_local = tid >> 4, jj = tid & 15;
  const int col = lv * 128 + jg * 16 + jj;
  const int bg = mt * 16 + b_local;

  for (int t = 0; t < T_STEPS; ++t) {
    const ushort_t* hptr = Hb + (size_t)(8 + t) * HB_ROW + brow * H_DIM + quad * 8;
    f32x4 acc = {0.f, 0.f, 0.f, 0.f};
    f32x4 accm = {0.f, 0.f, 0.f, 0.f};
#pragma unroll
    for (int ks = 0; ks < 12; ++ks) {
      bf16x8 a = *(const bf16x8*)(hptr + ks * 32);
      bf16x8 bb = *(const bf16x8*)(bptr + ks * 32);
      acc = __builtin_amdgcn_mfma_f32_16x16x32_bf16(a, bb, acc, 0, 0, 0);
      if (w == 0) {
        bf16x8 bm = *(const bf16x8*)(mwptr + ks * 32);
        accm = __builtin_amdgcn_mfma_f32_16x16x32_bf16(a, bm, accm, 0, 0, 0);
      }
    }
    const size_t xo = xoff + (size_t)t * D_IN;
    if (!is32) {
#pragma unroll
      for (int ks = 0; ks < 4; ++ks) {
        bf16x8 a = *(const bf16x8*)(xu + xo + ks * 32);
        bf16x8 bb = *(const bf16x8*)(bptr + (12 + ks) * 32);
        acc = __builtin_amdgcn_mfma_f32_16x16x32_bf16(a, bb, acc, 0, 0, 0);
        if (w == 0) {
          bf16x8 bm = *(const bf16x8*)(mwptr + (12 + ks) * 32);
          accm = __builtin_amdgcn_mfma_f32_16x16x32_bf16(a, bm, accm, 0, 0, 0);
        }
      }
    } else {
#pragma unroll
      for (int ks = 0; ks < 4; ++ks) {
        f32x4 fa = *(const f32x4*)(xf + xo + ks * 32);
        f32x4 fb = *(const f32x4*)(xf + xo + ks * 32 + 4);
        bf16x8 a;
#pragma unroll
        for (int j = 0; j < 4; ++j) { a[j] = (short)f2bf(fa[j]); a[4 + j] = (short)f2bf(fb[j]); }
        bf16x8 bb = *(const bf16x8*)(bptr + (12 + ks) * 32);
        acc = __builtin_amdgcn_mfma_f32_16x16x32_bf16(a, bb, acc, 0, 0, 0);
        if (w == 0) {
          bf16x8 bm = *(const bf16x8*)(mwptr + (12 + ks) * 32);
          accm = __builtin_amdgcn_mfma_f32_16x16x32_bf16(a, bm, accm, 0, 0, 0);
        }
      }
    }
#pragma unroll
    for (int r = 0; r < 4; ++r) {
      zbuf[w][quad * 4 + r][l15] = acc[r] + biasg;
      if (w == 0) zbuf[4][quad * 4 + r][l15] = accm[r] + biasm;
    }
    __syncthreads();

    {
      float z0 = zbuf[4][b_local][0], z1 = zbuf[4][b_local][1], z2 = zbuf[4][b_local][2];
      float z3 = zbuf[4][b_local][3], z4 = zbuf[4][b_local][4], z5 = zbuf[4][b_local][5];
      float mf = fmaxf(z0, fmaxf(z1, z2));
      float e0 = __expf(z0 - mf), e1 = __expf(z1 - mf), e2 = __expf(z2 - mf);
      float rs = 1.f / (e0 + e1 + e2);
      float p0 = e0 * rs, p1 = e1 * rs;
      float fm = (lv == 0) ? p0 : (lv == 1) ? (p0 + p1) : 1.f;
      float mi = fmaxf(z3, fmaxf(z4, z5));
      float g0 = __expf(z3 - mi), g1 = __expf(z4 - mi), g2 = __expf(z5 - mi);
      float ris = 1.f / (g0 + g1 + g2);
      float q1 = g1 * ris, q2 = g2 * ris;
      float im = (lv == 0) ? 1.f : (lv == 1) ? (q1 + q2) : q2;

      float fg = sigf(zbuf[0][b_local][jj]);
      float ig = sigf(zbuf[1][b_local][jj]);
      float og = sigf(zbuf[2][b_local][jj]);
      float ci = tanh_f(zbuf[3][b_local][jj]);
      float ov = fm * im;
      float co = cst[bg * H_DIM + col];
      float cn = co * (ov * fg + fm - ov) + ci * (ov * ig + im - ov);
      cst[bg * H_DIM + col] = cn;
      float h = og * tanh_f(cn);
      Hb[(size_t)(9 + t) * HB_ROW + bg * H_DIM + col] = f2bf(h);
      if (unit == 0 && jj == 0) {
        CD[(9 + t) * Bsz + bg] = 1.f - (2.f * p0 + p1 + 1.f) * (1.f / 3.f);
      }
    }
    __threadfence();
    __syncthreads();
    if (tid == 0)
      __hip_atomic_store(&flags[bid], t + 1, __ATOMIC_RELEASE, __HIP_MEMORY_SCOPE_AGENT);
    if (w == 0) {
      const int tgt = t + 1;
      while (true) {
        int v0 = __hip_atomic_load(&flags[lane], __ATOMIC_ACQUIRE, __HIP_MEMORY_SCOPE_AGENT);
        int v1 = __hip_atomic_load(&flags[lane + 64], __ATOMIC_ACQUIRE, __HIP_MEMORY_SCOPE_AGENT);
        int v2 = __hip_atomic_load(&flags[lane + 128], __ATOMIC_ACQUIRE, __HIP_MEMORY_SCOPE_AGENT);
        int mn = min(v0, min(v1, v2));
        if (__all(mn >= tgt)) break;
        __builtin_amdgcn_s_sleep(2);
      }
    }
    __syncthreads();
  }
}

// ---------------- B1: dis + theme (theme staged into d_out, native width) ----------------
__global__ __launch_bounds__(256) void k_b1(const ushort_t* __restrict__ Hb,
                                            const float* __restrict__ CD,
                                            float* __restrict__ disg,
                                            const ushort_t* __restrict__ Wsb,
                                            const float* __restrict__ bsf,
                                            const ushort_t* __restrict__ Wrsb,
                                            const float* __restrict__ brsf,
                                            void* __restrict__ out,
                                            const int* __restrict__ dflag) {
  __shared__ float disL[64][CONV_W];
  __shared__ ushort_t mL[64][H_DIM];
  __shared__ ushort_t uL[64][64];
  const int is32 = dflag[0];
  const int t = blockIdx.x >> 1;
  const int b0 = (blockIdx.x & 1) * 64;
  const int tid = threadIdx.x;

  if (tid < 64) {
    int b = tid;
    float s[CONV_W];
    float cum = 0.f, mx = -1e30f;
#pragma unroll
    for (int k = 0; k < CONV_W; ++k) {
      cum += CD[(t + k) * Bsz + b0 + b];
      s[k] = cum;
      mx = fmaxf(mx, cum);
    }
    float den = 0.f;
#pragma unroll
    for (int k = 0; k < CONV_W; ++k) { s[k] = __expf(s[k] - mx); den += s[k]; }
    float inv = 1.f / den;
#pragma unroll
    for (int k = 0; k < CONV_W; ++k) {
      float v = s[k] * inv;
      disL[b][k] = v;
      disg[(size_t)((t * Bsz) + b0 + b) * CONV_W + k] = v;
    }
  }
  __syncthreads();

  for (int ch = tid; ch < 64 * 48; ch += 256) {
    int b = ch / 48, ic = (ch % 48) * 8;
    float a[8] = {0.f, 0.f, 0.f, 0.f, 0.f, 0.f, 0.f, 0.f};
#pragma unroll
    for (int k = 0; k < CONV_W; ++k) {
      float dv = disL[b][k];
      ushort8 h8 = *(const ushort8*)(Hb + (size_t)(t + k) * HB_ROW + (b0 + b) * H_DIM + ic);
#pragma unroll
      for (int j = 0; j < 8; ++j) a[j] += dv * bf2f(h8[j]);
    }
    ushort8 mo;
#pragma unroll
    for (int j = 0; j < 8; ++j) mo[j] = f2bf(a[j] * 0.1f);
    *(ushort8*)(&mL[b][ic]) = mo;
  }
  __syncthreads();

  for (int idx = tid; idx < 64 * 64; idx += 256) {
    int b = idx >> 6, hs = idx & 63;
    float s = bsf[hs];
    for (int i = 0; i < H_DIM; ++i) s += bf2f(mL[b][i]) * bf2f(Wsb[i * 64 + hs]);
    uL[b][hs] = f2bf(fmaxf(s, 0.f));
  }
  __syncthreads();

  for (int idx = tid; idx < 64 * H_DIM; idx += 256) {
    int b = idx / H_DIM, o = idx % H_DIM;
    float s = brsf[o];
    for (int hs = 0; hs < 64; ++hs) s += bf2f(uL[b][hs]) * bf2f(Wrsb[hs * H_DIM + o]);
    float th = sigf(s);
    size_t oi = (size_t)(b0 + b) * (T_STEPS * H_DIM) + (size_t)t * H_DIM + o;
    if (is32) ((float*)out)[oi] = th; else ((ushort_t*)out)[oi] = f2bf(th);
  }
}

// ---------------- B2: conv GEMM (per-tap acc fold by dis) + final y ----------------
__global__ __launch_bounds__(256, 2) void k_b2(const ushort_t* __restrict__ Hb,
                                               const float* __restrict__ disg,
                                               const ushort_t* __restrict__ Wp,
                                               const float* __restrict__ bcf,
                                               void* __restrict__ out,
                                               const int* __restrict__ dflag) {
  __shared__ float disL[Bsz * CONV_W];
  const int is32 = dflag[0];
  const int bid = blockIdx.x;
  const int t = bid & 511, nb = bid >> 9;
  const int tid = threadIdx.x;
  const int w = tid >> 6, lane = tid & 63;
  const int l15 = lane & 15, quad = lane >> 4;

  for (int idx = tid; idx < Bsz * CONV_W; idx += 256)
    disL[idx] = disg[(size_t)t * Bsz * CONV_W + idx];
  __syncthreads();

  const int nbase = nb * 128 + w * 32;
  const ushort_t* wp0 = Wp + (size_t)(nbase + l15) * 3840 + quad * 8;
  const ushort_t* wp1 = Wp + (size_t)(nbase + 16 + l15) * 3840 + quad * 8;
  const ushort_t* hbase = Hb + (size_t)t * HB_ROW + l15 * H_DIM + quad * 8;

  f32x4 macc[8][2];
#pragma unroll
  for (int m = 0; m < 8; ++m) {
    macc[m][0] = f32x4{0.f, 0.f, 0.f, 0.f};
    macc[m][1] = f32x4{0.f, 0.f, 0.f, 0.f};
  }

  for (int tap = 0; tap < CONV_W; ++tap) {
    f32x4 pacc[8][2];
#pragma unroll
    for (int m = 0; m < 8; ++m) {
      pacc[m][0] = f32x4{0.f, 0.f, 0.f, 0.f};
      pacc[m][1] = f32x4{0.f, 0.f, 0.f, 0.f};
    }
    const ushort_t* hb = hbase + (size_t)tap * HB_ROW;
    const ushort_t* w0 = wp0 + tap * 384;
    const ushort_t* w1 = wp1 + tap * 384;
#pragma unroll
    for (int s = 0; s < 12; ++s) {
      bf16x8 bb0 = *(const bf16x8*)(w0 + s * 32);
      bf16x8 bb1 = *(const bf16x8*)(w1 + s * 32);
#pragma unroll
      for (int m = 0; m < 8; ++m) {
        bf16x8 a = *(const bf16x8*)(hb + (size_t)m * 16 * H_DIM + s * 32);
        pacc[m][0] = __builtin_amdgcn_mfma_f32_16x16x32_bf16(a, bb0, pacc[m][0], 0, 0, 0);
        pacc[m][1] = __builtin_amdgcn_mfma_f32_16x16x32_bf16(a, bb1, pacc[m][1], 0, 0, 0);
      }
    }
#pragma unroll
    for (int m = 0; m < 8; ++m) {
#pragma unroll
      for (int r = 0; r < 4; ++r) {
        float dv = disL[(m * 16 + quad * 4 + r) * CONV_W + tap];
        macc[m][0][r] += dv * pacc[m][0][r];
        macc[m][1][r] += dv * pacc[m][1][r];
      }
    }
  }

  float bc0 = bcf[nbase + l15];
  float bc1 = bcf[nbase + 16 + l15];
#pragma unroll
  for (int m = 0; m < 8; ++m) {
#pragma unroll
    for (int r = 0; r < 4; ++r) {
      int b = m * 16 + quad * 4 + r;
      size_t oidx = (size_t)b * (T_STEPS * H_DIM) + (size_t)t * H_DIM;
      int o0 = nbase + l15, o1 = o0 + 16;
      float c0 = macc[m][0][r] + bc0;
      float c1 = macc[m][1][r] + bc1;
      float h0 = bf2f(Hb[(size_t)(9 + t) * HB_ROW + b * H_DIM + o0]);
      float h1 = bf2f(Hb[(size_t)(9 + t) * HB_ROW + b * H_DIM + o1]);
      if (is32) {
        float th0 = ((float*)out)[oidx + o0];
        float th1 = ((float*)out)[oidx + o1];
        ((float*)out)[oidx + o0] = th0 * c0 + h0;
        ((float*)out)[oidx + o1] = th1 * c1 + h1;
      } else {
        float th0 = bf2f(((ushort_t*)out)[oidx + o0]);
        float th1 = bf2f(((ushort_t*)out)[oidx + o1]);
        ((ushort_t*)out)[oidx + o0] = f2bf(th0 * c0 + h0);
        ((ushort_t*)out)[oidx + o1] = f2bf(th1 * c1 + h1);
      }
    }
  }
}

extern "C" void kernel_launch(void* const* d_in, const int* in_sizes, int n_in,
                              void* d_out, int out_size, void* d_ws, size_t ws_size,
                              hipStream_t stream) {
  const void* x = d_in[0];
  // d_in[1] lengths: unused by forward
  const void* Wk = d_in[2];
  const void* bk = d_in[3];
  const void* Wr = d_in[4];
  const void* br = d_in[5];
  const void* Ws = d_in[6];
  const void* bs = d_in[7];
  const void* Wrs = d_in[8];
  const void* brs = d_in[9];
  const void* Wc = d_in[10];
  const void* bc = d_in[11];

  char* ws = (char*)d_ws;
  size_t off = 0;
  auto alloc = [&](size_t bytes) -> void* {
    off = (off + 255) & ~(size_t)255;
    void* p = ws + off;
    off += bytes;
    return p;
  };
  ushort_t* Hb = (ushort_t*)alloc((size_t)TP * HB_ROW * 2);        // 51.2 MB
  float* CD = (float*)alloc((size_t)TP * Bsz * 4);
  float* cst = (float*)alloc((size_t)Bsz * H_DIM * 4);
  ushort_t* Wt = (ushort_t*)alloc((size_t)1552 * 512 * 2);
  float* bias = (float*)alloc((size_t)1552 * 4);
  ushort_t* Wp = (ushort_t*)alloc((size_t)H_DIM * 3840 * 2);
  float* disg = (float*)alloc((size_t)T_STEPS * Bsz * CONV_W * 4);
  ushort_t* Wsb = (ushort_t*)alloc(24576 * 2);
  ushort_t* Wrsb = (ushort_t*)alloc(24576 * 2);
  float* bsf = (float*)alloc(64 * 4);
  float* brsf = (float*)alloc(384 * 4);
  float* bcf = (float*)alloc(384 * 4);
  int* flags = (int*)alloc(256 * 4);
  int* dflag = (int*)alloc(64 * 4);
  (void)ws_size; (void)in_sizes; (void)n_in; (void)out_size;

  k_detect<<<1, 64, 0, stream>>>((const uint32*)x, dflag);
  k_zero<<<1728, 256, 0, stream>>>(Hb, CD, cst, flags);
  k_packwt<<<3104, 256, 0, stream>>>(Wk, bk, Wr, br, Wt, bias, dflag);
  k_packwp<<<5760, 256, 0, stream>>>(Wc, Wp, dflag);
  k_packsml<<<196, 256, 0, stream>>>(Ws, bs, Wrs, brs, bc, Wsb, bsf, Wrsb, brsf, bcf, dflag);
  k_phaseA<<<192, 256, 0, stream>>>(x, Wt, bias, Hb, CD, cst, flags, dflag);
  k_b1<<<1024, 256, 0, stream>>>(Hb, CD, disg, Wsb, bsf, Wrsb, brsf, d_out, dflag);
  k_b2<<<1536, 256, 0, stream>>>(Hb, disg, Wp, bcf, d_out, dflag);
}

// Round 3
// 5949.997 us; speedup vs baseline: 3.2023x; 3.2023x over previous
//
#include <hip/hip_runtime.h>

typedef unsigned short ushort_t;
typedef unsigned int uint32;
typedef unsigned long long uint64;
typedef __attribute__((ext_vector_type(8))) short bf16x8;
typedef __attribute__((ext_vector_type(8))) unsigned short ushort8;
typedef __attribute__((ext_vector_type(4))) float f32x4;

#define Bsz 128
#define T_STEPS 512
#define D_IN 128
#define H_DIM 384
#define G_DIM 1542
#define CONV_W 10
#define HB_ROW 49152   // Bsz*H_DIM
#define TP 521         // T+9 (9 zero-pad rows in front)

__device__ __forceinline__ float bf2f(ushort_t u) {
  return __builtin_bit_cast(float, (uint32)u << 16);
}
__device__ __forceinline__ ushort_t f2bf(float f) {
  uint32 u = __builtin_bit_cast(uint32, f);
  u += 0x7fffu + ((u >> 16) & 1u);
  return (ushort_t)(u >> 16);
}
__device__ __forceinline__ float sigf(float x) { return 1.f / (1.f + __expf(-x)); }
__device__ __forceinline__ float tanh_f(float x) { return 1.f - 2.f / (1.f + __expf(2.f * x)); }
__device__ __forceinline__ float ldg_f(const void* p, size_t i, int f32) {
  return f32 ? ((const float*)p)[i] : bf2f(((const ushort_t*)p)[i]);
}

// ---------------- dtype detector ----------------
__global__ __launch_bounds__(64) void k_detect(const uint32* __restrict__ xw, int* __restrict__ dflag) {
  int lane = threadIdx.x;
  int cnt = 0;
  for (int i = 0; i < 16; ++i) {
    uint32 v = xw[lane * 16 + i];
    uint32 e = (v >> 7) & 0xFFu;
    cnt += (e == 0u || (e >= 0x70u && e <= 0x8Eu)) ? 1 : 0;
  }
  for (int off = 32; off; off >>= 1) cnt += __shfl_down(cnt, off);
  if (lane == 0) dflag[0] = (cnt < 700) ? 1 : 0;   // 1=f32, 0=bf16
}

// ---------------- init ----------------
__global__ __launch_bounds__(256) void k_zero(ushort_t* Hb, float* CD, int* flags) {
  int idx = blockIdx.x * 256 + threadIdx.x;
  if (idx < 9 * HB_ROW) Hb[idx] = 0;
  if (idx < 9 * Bsz) CD[idx] = 0.f;
  if (idx < 256) flags[idx] = 0;
}

// ---------------- pack recurrent weights ----------------
__global__ __launch_bounds__(256) void k_packwt(const void* __restrict__ Wk, const void* __restrict__ bk,
                                                const void* __restrict__ Wr, const void* __restrict__ br,
                                                ushort_t* __restrict__ Wt, float* __restrict__ bias,
                                                const int* __restrict__ dflag) {
  const int is32 = dflag[0];
  int idx = blockIdx.x * 256 + threadIdx.x;   // 1552*512
  int c = idx >> 9, k = idx & 511;
  int xc = (c < 1536) ? (c + 6) : (c - 1536);
  float v = 0.f;
  if (c < 1542)
    v = (k < 384) ? ldg_f(Wr, (size_t)k * G_DIM + xc, is32)
                  : ldg_f(Wk, (size_t)(k - 384) * G_DIM + xc, is32);
  Wt[idx] = f2bf(v);
  if (k == 0) {
    float bv = 0.f;
    if (c < 1542)
      bv = ldg_f(bk, xc, is32) + ldg_f(br, xc, is32)
         + ldg_f(Wk, (size_t)128 * G_DIM + xc, is32) + ldg_f(Wr, (size_t)384 * G_DIM + xc, is32);
    bias[c] = bv;
  }
}

// ---------------- pack conv weights ----------------
__global__ __launch_bounds__(256) void k_packwp(const void* __restrict__ Wc, ushort_t* __restrict__ Wp,
                                                const int* __restrict__ dflag) {
  const int is32 = dflag[0];
  int idx = blockIdx.x * 256 + threadIdx.x;   // 384*3840
  int o = idx / 3840, kk = idx % 3840;
  int k = kk / 384, i = kk % 384;
  Wp[idx] = f2bf(ldg_f(Wc, (size_t)o * 3840 + i * CONV_W + k, is32));
}

// ---------------- pack small tensors ----------------
__global__ __launch_bounds__(256) void k_packsml(const void* Ws, const void* bs, const void* Wrs,
                                                 const void* brs, const void* bc,
                                                 ushort_t* Wsb, float* bsf, ushort_t* Wrsb,
                                                 float* brsf, float* bcf, const int* dflag) {
  const int is32 = dflag[0];
  int idx = blockIdx.x * 256 + threadIdx.x;
  if (idx < 24576) Wsb[idx] = f2bf(ldg_f(Ws, idx, is32));
  else if (idx < 49152) Wrsb[idx - 24576] = f2bf(ldg_f(Wrs, idx - 24576, is32));
  else if (idx < 49152 + 64) bsf[idx - 49152] = ldg_f(bs, idx - 49152, is32);
  else if (idx < 49216 + 384) brsf[idx - 49216] = ldg_f(brs, idx - 49216, is32);
  else if (idx < 49600 + 384) bcf[idx - 49600] = ldg_f(bc, idx - 49600, is32);
}

// ---------------- phase A: 8 independent chains (mt groups) of 24 blocks ----------------
// mt = bid&7 (XCD-aligned under round-robin dispatch), unit = bid>>3 -> (lv,jg).
// h exchange via sc1 (agent-relaxed) loads/stores: no fences, weights stay hot in L2.
__global__ __launch_bounds__(256) void k_phaseA(const void* __restrict__ xv,
                                                const ushort_t* __restrict__ Wt,
                                                const float* __restrict__ bias,
                                                ushort_t* __restrict__ Hb,
                                                float* __restrict__ CD,
                                                int* __restrict__ flags,
                                                const int* __restrict__ dflag) {
  __shared__ float zbuf[5][16][17];
  const int is32 = dflag[0];
  const int bid = blockIdx.x;
  const int mt = bid & 7;
  const int unit = bid >> 3;           // 0..23
  const int lv = unit / 8, jg = unit % 8;
  const int tid = threadIdx.x;
  const int w = tid >> 6, lane = tid & 63;
  const int l15 = lane & 15, quad = lane >> 4;

  const int brow = mt * 16 + l15;
  const int cb = (lv + 3 * w) * 128 + jg * 16;
  const ushort_t* bptr = Wt + (size_t)(cb + l15) * 512 + quad * 8;
  const ushort_t* mwptr = Wt + (size_t)(1536 + l15) * 512 + quad * 8;
  const size_t xoff = (size_t)brow * (T_STEPS * D_IN) + quad * 8;
  const ushort_t* xu = (const ushort_t*)xv;
  const float* xf = (const float*)xv;
  const float biasg = bias[cb + l15];
  const float biasm = bias[1536 + l15];

  const int b_local = tid >> 4, jj = tid & 15;
  const int col = lv * 128 + jg * 16 + jj;
  const int bg = mt * 16 + b_local;
  float creg = 0.f;                    // c state lives in a register

  int* gflags = flags + mt * 32;       // 24 flags per group, own cachelines

  for (int t = 0; t < T_STEPS; ++t) {
    // ---- x-part first (independent of h_{t-1}) ----
    f32x4 acc = {0.f, 0.f, 0.f, 0.f};
    f32x4 accm = {0.f, 0.f, 0.f, 0.f};
    const size_t xo = xoff + (size_t)t * D_IN;
    if (!is32) {
#pragma unroll
      for (int ks = 0; ks < 4; ++ks) {
        bf16x8 a = *(const bf16x8*)(xu + xo + ks * 32);
        bf16x8 bb = *(const bf16x8*)(bptr + (12 + ks) * 32);
        acc = __builtin_amdgcn_mfma_f32_16x16x32_bf16(a, bb, acc, 0, 0, 0);
        if (w == 0) {
          bf16x8 bm = *(const bf16x8*)(mwptr + (12 + ks) * 32);
          accm = __builtin_amdgcn_mfma_f32_16x16x32_bf16(a, bm, accm, 0, 0, 0);
        }
      }
    } else {
#pragma unroll
      for (int ks = 0; ks < 4; ++ks) {
        f32x4 fa = *(const f32x4*)(xf + xo + ks * 32);
        f32x4 fb = *(const f32x4*)(xf + xo + ks * 32 + 4);
        bf16x8 a;
#pragma unroll
        for (int j = 0; j < 4; ++j) { a[j] = (short)f2bf(fa[j]); a[4 + j] = (short)f2bf(fb[j]); }
        bf16x8 bb = *(const bf16x8*)(bptr + (12 + ks) * 32);
        acc = __builtin_amdgcn_mfma_f32_16x16x32_bf16(a, bb, acc, 0, 0, 0);
        if (w == 0) {
          bf16x8 bm = *(const bf16x8*)(mwptr + (12 + ks) * 32);
          accm = __builtin_amdgcn_mfma_f32_16x16x32_bf16(a, bm, accm, 0, 0, 0);
        }
      }
    }

    // ---- wait for h_{t-1}: every wave polls its group's 24 flags (sc1, no fences) ----
    if (t > 0) {
      while (true) {
        int ok = 1;
        if (lane < 24) {
          int v = __hip_atomic_load(&gflags[lane], __ATOMIC_RELAXED, __HIP_MEMORY_SCOPE_AGENT);
          ok = (v >= t) ? 1 : 0;
        }
        if (__all(ok)) break;
      }
    }

    // ---- h-part MFMAs (h_{t-1} via sc1 8B loads) ----
    const ushort_t* hptr = Hb + (size_t)(8 + t) * HB_ROW + brow * H_DIM + quad * 8;
#pragma unroll
    for (int ks = 0; ks < 12; ++ks) {
      uint64 lo = __hip_atomic_load((const uint64*)(hptr + ks * 32), __ATOMIC_RELAXED, __HIP_MEMORY_SCOPE_AGENT);
      uint64 hi = __hip_atomic_load((const uint64*)(hptr + ks * 32 + 4), __ATOMIC_RELAXED, __HIP_MEMORY_SCOPE_AGENT);
      bf16x8 a;
      ((uint64*)&a)[0] = lo;
      ((uint64*)&a)[1] = hi;
      bf16x8 bb = *(const bf16x8*)(bptr + ks * 32);
      acc = __builtin_amdgcn_mfma_f32_16x16x32_bf16(a, bb, acc, 0, 0, 0);
      if (w == 0) {
        bf16x8 bm = *(const bf16x8*)(mwptr + ks * 32);
        accm = __builtin_amdgcn_mfma_f32_16x16x32_bf16(a, bm, accm, 0, 0, 0);
      }
    }
#pragma unroll
    for (int r = 0; r < 4; ++r) {
      zbuf[w][quad * 4 + r][l15] = acc[r] + biasg;
      if (w == 0) zbuf[4][quad * 4 + r][l15] = accm[r] + biasm;
    }
    __syncthreads();   // S2: zbuf ready

    // ---- elementwise gates (c in register) ----
    {
      float z0 = zbuf[4][b_local][0], z1 = zbuf[4][b_local][1], z2 = zbuf[4][b_local][2];
      float z3 = zbuf[4][b_local][3], z4 = zbuf[4][b_local][4], z5 = zbuf[4][b_local][5];
      float mf = fmaxf(z0, fmaxf(z1, z2));
      float e0 = __expf(z0 - mf), e1 = __expf(z1 - mf), e2 = __expf(z2 - mf);
      float rs = 1.f / (e0 + e1 + e2);
      float p0 = e0 * rs, p1 = e1 * rs;
      float fm = (lv == 0) ? p0 : (lv == 1) ? (p0 + p1) : 1.f;
      float mi = fmaxf(z3, fmaxf(z4, z5));
      float g0 = __expf(z3 - mi), g1 = __expf(z4 - mi), g2 = __expf(z5 - mi);
      float ris = 1.f / (g0 + g1 + g2);
      float q1 = g1 * ris, q2 = g2 * ris;
      float im = (lv == 0) ? 1.f : (lv == 1) ? (q1 + q2) : q2;

      float fg = sigf(zbuf[0][b_local][jj]);
      float ig = sigf(zbuf[1][b_local][jj]);
      float og = sigf(zbuf[2][b_local][jj]);
      float ci = tanh_f(zbuf[3][b_local][jj]);
      float ov = fm * im;
      float cn = creg * (ov * fg + fm - ov) + ci * (ov * ig + im - ov);
      creg = cn;
      float h = og * tanh_f(cn);

      // pack 2 bf16 per 4B sc1 store (even jj stores self+partner)
      float hp = __shfl_xor(h, 1);
      if (!(jj & 1)) {
        uint32 packed = (uint32)f2bf(h) | ((uint32)f2bf(hp) << 16);
        uint32* dst = (uint32*)(Hb + (size_t)(9 + t) * HB_ROW + bg * H_DIM + col);
        __hip_atomic_store(dst, packed, __ATOMIC_RELAXED, __HIP_MEMORY_SCOPE_AGENT);
      }
      if (unit == 0 && jj == 0) {
        float cd = 1.f - (2.f * p0 + p1 + 1.f) * (1.f / 3.f);
        __hip_atomic_store(&CD[(9 + t) * Bsz + bg], cd, __ATOMIC_RELAXED, __HIP_MEMORY_SCOPE_AGENT);
      }
    }
    __syncthreads();   // S3: drains all waves' vmem stores (compiler emits vmcnt(0) before s_barrier)
    if (tid == 0)
      __hip_atomic_store(&gflags[unit], t + 1, __ATOMIC_RELAXED, __HIP_MEMORY_SCOPE_AGENT);
  }
}

// ---------------- B1: dis + theme ----------------
__global__ __launch_bounds__(256) void k_b1(const ushort_t* __restrict__ Hb,
                                            const float* __restrict__ CD,
                                            float* __restrict__ disg,
                                            const ushort_t* __restrict__ Wsb,
                                            const float* __restrict__ bsf,
                                            const ushort_t* __restrict__ Wrsb,
                                            const float* __restrict__ brsf,
                                            void* __restrict__ out,
                                            const int* __restrict__ dflag) {
  __shared__ float disL[64][CONV_W];
  __shared__ ushort_t mL[64][H_DIM];
  __shared__ ushort_t uL[64][64];
  const int is32 = dflag[0];
  const int t = blockIdx.x >> 1;
  const int b0 = (blockIdx.x & 1) * 64;
  const int tid = threadIdx.x;

  if (tid < 64) {
    int b = tid;
    float s[CONV_W];
    float cum = 0.f, mx = -1e30f;
#pragma unroll
    for (int k = 0; k < CONV_W; ++k) {
      cum += CD[(t + k) * Bsz + b0 + b];
      s[k] = cum;
      mx = fmaxf(mx, cum);
    }
    float den = 0.f;
#pragma unroll
    for (int k = 0; k < CONV_W; ++k) { s[k] = __expf(s[k] - mx); den += s[k]; }
    float inv = 1.f / den;
#pragma unroll
    for (int k = 0; k < CONV_W; ++k) {
      float v = s[k] * inv;
      disL[b][k] = v;
      disg[(size_t)((t * Bsz) + b0 + b) * CONV_W + k] = v;
    }
  }
  __syncthreads();

  for (int ch = tid; ch < 64 * 48; ch += 256) {
    int b = ch / 48, ic = (ch % 48) * 8;
    float a[8] = {0.f, 0.f, 0.f, 0.f, 0.f, 0.f, 0.f, 0.f};
#pragma unroll
    for (int k = 0; k < CONV_W; ++k) {
      float dv = disL[b][k];
      ushort8 h8 = *(const ushort8*)(Hb + (size_t)(t + k) * HB_ROW + (b0 + b) * H_DIM + ic);
#pragma unroll
      for (int j = 0; j < 8; ++j) a[j] += dv * bf2f(h8[j]);
    }
    ushort8 mo;
#pragma unroll
    for (int j = 0; j < 8; ++j) mo[j] = f2bf(a[j] * 0.1f);
    *(ushort8*)(&mL[b][ic]) = mo;
  }
  __syncthreads();

  for (int idx = tid; idx < 64 * 64; idx += 256) {
    int b = idx >> 6, hs = idx & 63;
    float s = bsf[hs];
    for (int i = 0; i < H_DIM; ++i) s += bf2f(mL[b][i]) * bf2f(Wsb[i * 64 + hs]);
    uL[b][hs] = f2bf(fmaxf(s, 0.f));
  }
  __syncthreads();

  for (int idx = tid; idx < 64 * H_DIM; idx += 256) {
    int b = idx / H_DIM, o = idx % H_DIM;
    float s = brsf[o];
    for (int hs = 0; hs < 64; ++hs) s += bf2f(uL[b][hs]) * bf2f(Wrsb[hs * H_DIM + o]);
    float th = sigf(s);
    size_t oi = (size_t)(b0 + b) * (T_STEPS * H_DIM) + (size_t)t * H_DIM + o;
    if (is32) ((float*)out)[oi] = th; else ((ushort_t*)out)[oi] = f2bf(th);
  }
}

// ---------------- B2: conv GEMM + final y ----------------
__global__ __launch_bounds__(256, 2) void k_b2(const ushort_t* __restrict__ Hb,
                                               const float* __restrict__ disg,
                                               const ushort_t* __restrict__ Wp,
                                               const float* __restrict__ bcf,
                                               void* __restrict__ out,
                                               const int* __restrict__ dflag) {
  __shared__ float disL[Bsz * CONV_W];
  const int is32 = dflag[0];
  const int bid = blockIdx.x;
  const int t = bid & 511, nb = bid >> 9;
  const int tid = threadIdx.x;
  const int w = tid >> 6, lane = tid & 63;
  const int l15 = lane & 15, quad = lane >> 4;

  for (int idx = tid; idx < Bsz * CONV_W; idx += 256)
    disL[idx] = disg[(size_t)t * Bsz * CONV_W + idx];
  __syncthreads();

  const int nbase = nb * 128 + w * 32;
  const ushort_t* wp0 = Wp + (size_t)(nbase + l15) * 3840 + quad * 8;
  const ushort_t* wp1 = Wp + (size_t)(nbase + 16 + l15) * 3840 + quad * 8;
  const ushort_t* hbase = Hb + (size_t)t * HB_ROW + l15 * H_DIM + quad * 8;

  f32x4 macc[8][2];
#pragma unroll
  for (int m = 0; m < 8; ++m) {
    macc[m][0] = f32x4{0.f, 0.f, 0.f, 0.f};
    macc[m][1] = f32x4{0.f, 0.f, 0.f, 0.f};
  }

  for (int tap = 0; tap < CONV_W; ++tap) {
    f32x4 pacc[8][2];
#pragma unroll
    for (int m = 0; m < 8; ++m) {
      pacc[m][0] = f32x4{0.f, 0.f, 0.f, 0.f};
      pacc[m][1] = f32x4{0.f, 0.f, 0.f, 0.f};
    }
    const ushort_t* hb = hbase + (size_t)tap * HB_ROW;
    const ushort_t* w0 = wp0 + tap * 384;
    const ushort_t* w1 = wp1 + tap * 384;
#pragma unroll
    for (int s = 0; s < 12; ++s) {
      bf16x8 bb0 = *(const bf16x8*)(w0 + s * 32);
      bf16x8 bb1 = *(const bf16x8*)(w1 + s * 32);
#pragma unroll
      for (int m = 0; m < 8; ++m) {
        bf16x8 a = *(const bf16x8*)(hb + (size_t)m * 16 * H_DIM + s * 32);
        pacc[m][0] = __builtin_amdgcn_mfma_f32_16x16x32_bf16(a, bb0, pacc[m][0], 0, 0, 0);
        pacc[m][1] = __builtin_amdgcn_mfma_f32_16x16x32_bf16(a, bb1, pacc[m][1], 0, 0, 0);
      }
    }
#pragma unroll
    for (int m = 0; m < 8; ++m) {
#pragma unroll
      for (int r = 0; r < 4; ++r) {
        float dv = disL[(m * 16 + quad * 4 + r) * CONV_W + tap];
        macc[m][0][r] += dv * pacc[m][0][r];
        macc[m][1][r] += dv * pacc[m][1][r];
      }
    }
  }

  float bc0 = bcf[nbase + l15];
  float bc1 = bcf[nbase + 16 + l15];
#pragma unroll
  for (int m = 0; m < 8; ++m) {
#pragma unroll
    for (int r = 0; r < 4; ++r) {
      int b = m * 16 + quad * 4 + r;
      size_t oidx = (size_t)b * (T_STEPS * H_DIM) + (size_t)t * H_DIM;
      int o0 = nbase + l15, o1 = o0 + 16;
      float c0 = macc[m][0][r] + bc0;
      float c1 = macc[m][1][r] + bc1;
      float h0 = bf2f(Hb[(size_t)(9 + t) * HB_ROW + b * H_DIM + o0]);
      float h1 = bf2f(Hb[(size_t)(9 + t) * HB_ROW + b * H_DIM + o1]);
      if (is32) {
        float th0 = ((float*)out)[oidx + o0];
        float th1 = ((float*)out)[oidx + o1];
        ((float*)out)[oidx + o0] = th0 * c0 + h0;
        ((float*)out)[oidx + o1] = th1 * c1 + h1;
      } else {
        float th0 = bf2f(((ushort_t*)out)[oidx + o0]);
        float th1 = bf2f(((ushort_t*)out)[oidx + o1]);
        ((ushort_t*)out)[oidx + o0] = f2bf(th0 * c0 + h0);
        ((ushort_t*)out)[oidx + o1] = f2bf(th1 * c1 + h1);
      }
    }
  }
}

extern "C" void kernel_launch(void* const* d_in, const int* in_sizes, int n_in,
                              void* d_out, int out_size, void* d_ws, size_t ws_size,
                              hipStream_t stream) {
  const void* x = d_in[0];
  const void* Wk = d_in[2];
  const void* bk = d_in[3];
  const void* Wr = d_in[4];
  const void* br = d_in[5];
  const void* Ws = d_in[6];
  const void* bs = d_in[7];
  const void* Wrs = d_in[8];
  const void* brs = d_in[9];
  const void* Wc = d_in[10];
  const void* bc = d_in[11];

  char* ws = (char*)d_ws;
  size_t off = 0;
  auto alloc = [&](size_t bytes) -> void* {
    off = (off + 255) & ~(size_t)255;
    void* p = ws + off;
    off += bytes;
    return p;
  };
  ushort_t* Hb = (ushort_t*)alloc((size_t)TP * HB_ROW * 2);
  float* CD = (float*)alloc((size_t)TP * Bsz * 4);
  ushort_t* Wt = (ushort_t*)alloc((size_t)1552 * 512 * 2);
  float* bias = (float*)alloc((size_t)1552 * 4);
  ushort_t* Wp = (ushort_t*)alloc((size_t)H_DIM * 3840 * 2);
  float* disg = (float*)alloc((size_t)T_STEPS * Bsz * CONV_W * 4);
  ushort_t* Wsb = (ushort_t*)alloc(24576 * 2);
  ushort_t* Wrsb = (ushort_t*)alloc(24576 * 2);
  float* bsf = (float*)alloc(64 * 4);
  float* brsf = (float*)alloc(384 * 4);
  float* bcf = (float*)alloc(384 * 4);
  int* flags = (int*)alloc(256 * 4);
  int* dflag = (int*)alloc(64 * 4);
  (void)ws_size; (void)in_sizes; (void)n_in; (void)out_size;

  k_detect<<<1, 64, 0, stream>>>((const uint32*)x, dflag);
  k_zero<<<1728, 256, 0, stream>>>(Hb, CD, flags);
  k_packwt<<<3104, 256, 0, stream>>>(Wk, bk, Wr, br, Wt, bias, dflag);
  k_packwp<<<5760, 256, 0, stream>>>(Wc, Wp, dflag);
  k_packsml<<<196, 256, 0, stream>>>(Ws, bs, Wrs, brs, bc, Wsb, bsf, Wrsb, brsf, bcf, dflag);
  k_phaseA<<<192, 256, 0, stream>>>(x, Wt, bias, Hb, CD, flags, dflag);
  k_b1<<<1024, 256, 0, stream>>>(Hb, CD, disg, Wsb, bsf, Wrsb, brsf, d_out, dflag);
  k_b2<<<1536, 256, 0, stream>>>(Hb, disg, Wp, bcf, d_out, dflag);
}